// Round 8
// baseline (2533.235 us; speedup 1.0000x reference)
//
#include <hip/hip_runtime.h>
#include <math.h>

#define T_STEPS 4096
#define NB 16          // batch
#define NH 256         // hidden
#define BH (NB * NH)   // 4096 floats per time step
#define DT_STEP 0.1f

typedef __attribute__((ext_vector_type(8))) short short8;
typedef __attribute__((ext_vector_type(4))) float f32x4;

// lgkm-only barrier: cross-wave comm is LDS-only, so skip the vmcnt(0) drain
// (hidden-store / u-prefetch keep flying across steps).
#define LBAR() asm volatile("s_waitcnt lgkmcnt(0)\n\ts_barrier" ::: "memory")

// ---------------- expm via Taylor series ----------------
__global__ __launch_bounds__(1024) void k_init_S(const float* __restrict__ A,
                                                 float* __restrict__ S) {
    int idx = blockIdx.x * 1024 + threadIdx.x;
    int i = idx >> 8, j = idx & 255;
    S[idx] = A[idx] + (i == j ? 1.0f : 0.0f);
}

__global__ __launch_bounds__(256) void k_expm_term(const float* __restrict__ Pprev,
                                                   const float* __restrict__ A,
                                                   float* __restrict__ Pnew,
                                                   float* __restrict__ S,
                                                   float invk) {
    __shared__ float prow[256];
    int i = blockIdx.x, j = threadIdx.x;
    prow[j] = Pprev[i * 256 + j];
    __syncthreads();
    float acc = 0.f;
#pragma unroll 8
    for (int m = 0; m < 256; ++m) acc = fmaf(prow[m], A[m * 256 + j], acc);
    float v = acc * invk;
    Pnew[i * 256 + j] = v;
    S[i * 256 + j] += v;
}

// ---------------- row-blocked GEMM (unchanged, works) ----------------
__global__ __launch_bounds__(256) void k_gemm_rows(const float* __restrict__ X,
                                                   const float* __restrict__ Wm,
                                                   const float* __restrict__ bias,
                                                   float* __restrict__ Out) {
    __shared__ float4 xs4[16][64];
    const int tid = threadIdx.x;
    const long r0 = (long)blockIdx.x * 16;
    float* xs = (float*)xs4;
#pragma unroll
    for (int rr = 0; rr < 16; ++rr) xs[rr * 256 + tid] = X[(r0 + rr) * 256 + tid];
    __syncthreads();

    float acc[16];
#pragma unroll
    for (int rr = 0; rr < 16; ++rr) acc[rr] = 0.f;

    const float4* wrow = (const float4*)(Wm + tid * 256);
    for (int d4 = 0; d4 < 64; ++d4) {
        float4 w = wrow[d4];
#pragma unroll
        for (int rr = 0; rr < 16; ++rr) {
            float4 xv = xs4[rr][d4];
            acc[rr] = fmaf(w.x, xv.x, acc[rr]);
            acc[rr] = fmaf(w.y, xv.y, acc[rr]);
            acc[rr] = fmaf(w.z, xv.z, acc[rr]);
            acc[rr] = fmaf(w.w, xv.w, acc[rr]);
        }
    }
    float b = bias[tid];
#pragma unroll
    for (int rr = 0; rr < 16; ++rr) Out[(r0 + rr) * 256 + tid] = acc[rr] + b;
}

// ---------------- MFMA scan: one block (CU) per batch ----------------
// y = Wexp@h = h + E@h with E = Wexp - I (|E|~0.01). h kept exact in f32
// registers; only E·h goes through bf16 MFMA (16x16x32, M=1 real row).
// 16 waves: wave w owns output cols 16w..16w+15 (B-frag = E[n][k], resident).
// h exchanged via LDS in A-fragment-linear layout. 4 independent 2-long MFMA
// chains (vs one 8-chain) to cut serial MFMA latency. lgkm-only barrier.
__global__ __launch_bounds__(1024, 4)
void k_scan_mfma(const float* __restrict__ u,
                 const float* __restrict__ S,   // Wexp (f32)
                 float* __restrict__ hidden,
                 float* __restrict__ hfin) {
    const int b   = blockIdx.x;
    const int tid = threadIdx.x;
    const int w   = tid >> 6;            // wave = n-tile
    const int l   = tid & 63;
    const int n   = (w << 4) | (l & 15); // E row this lane serves (B-frag col)
    const int kg  = l >> 4;              // k-group 0..3

    __shared__ uint4 lds4[1152];         // 2 x (8 kt x 1152B) = 18432 B
    char* lds = (char*)lds4;
    for (int i = tid; i < 1152; i += 1024) lds4[i] = uint4{0, 0, 0, 0};

    // ---- B-fragments: E[n][kt*32+kg*8 .. +7] as packed bf16 (resident) ----
    union Frag { unsigned int u[4]; short8 v; };
    Frag ef[8];
#pragma unroll
    for (int kt = 0; kt < 8; ++kt) {
        const int k0 = kt * 32 + kg * 8;
        const float* sp = S + (size_t)n * 256 + k0;
        float e[8];
#pragma unroll
        for (int j = 0; j < 8; ++j)
            e[j] = sp[j] - ((n == k0 + j) ? 1.0f : 0.0f);
#pragma unroll
        for (int r2 = 0; r2 < 4; ++r2) {
            unsigned int pk;
            asm volatile("v_cvt_pk_bf16_f32 %0, %1, %2"
                         : "=v"(pk) : "v"(e[2 * r2]), "v"(e[2 * r2 + 1]));
            ef[kt].u[r2] = pk;
        }
    }

    // ---- A-fragments: persistent, zero except the 4 data lanes ----
    Frag af[8];
#pragma unroll
    for (int kt = 0; kt < 8; ++kt) {
        af[kt].u[0] = 0; af[kt].u[1] = 0; af[kt].u[2] = 0; af[kt].u[3] = 0;
    }
    const bool areal = ((l & 15) == 0);
    const int  abase = l * 16 + kg * 32;       // + kt*1152 + dbuf

    // ---- writer lanes: one h element each (col = n) ----
    const bool wr  = (l < 16);
    const int  col = (w << 4) | l;             // == n for l<16
    const int  wg  = (col >> 3) & 3;
    const int  wby = (col >> 5) * 1152 + wg * 288 + ((col & 7) >> 1) * 4;

    const float* up = u + (size_t)b * NH + col;
    float* hp = hidden + (size_t)b * NH + col;

    float hval = 0.f, u_cur = 0.f, u_nxt = 0.f;
    if (wr) {
        u_cur = up[0];
        u_nxt = up[BH];
    }
    __syncthreads();

    int roff = 0;                               // read buffer offset (0 / 9216)
    for (int t = 0; t < T_STEPS; ++t) {
        const int tpre = (t + 2 < T_STEPS) ? (t + 2) : (T_STEPS - 1);
        float u_n2 = 0.f;
        if (wr) u_n2 = up[(size_t)tpre * BH];

        if (areal) {
#pragma unroll
            for (int kt = 0; kt < 8; ++kt)
                af[kt].v = *(const short8*)(lds + roff + kt * 1152 + abase);
        }

        // 4 independent 2-long chains -> serial MFMA latency ~2x not 8x
        f32x4 ac0 = {0.f, 0.f, 0.f, 0.f};
        f32x4 ac1 = {0.f, 0.f, 0.f, 0.f};
        f32x4 ac2 = {0.f, 0.f, 0.f, 0.f};
        f32x4 ac3 = {0.f, 0.f, 0.f, 0.f};
        ac0 = __builtin_amdgcn_mfma_f32_16x16x32_bf16(af[0].v, ef[0].v, ac0, 0, 0, 0);
        ac1 = __builtin_amdgcn_mfma_f32_16x16x32_bf16(af[2].v, ef[2].v, ac1, 0, 0, 0);
        ac2 = __builtin_amdgcn_mfma_f32_16x16x32_bf16(af[4].v, ef[4].v, ac2, 0, 0, 0);
        ac3 = __builtin_amdgcn_mfma_f32_16x16x32_bf16(af[6].v, ef[6].v, ac3, 0, 0, 0);
        ac0 = __builtin_amdgcn_mfma_f32_16x16x32_bf16(af[1].v, ef[1].v, ac0, 0, 0, 0);
        ac1 = __builtin_amdgcn_mfma_f32_16x16x32_bf16(af[3].v, ef[3].v, ac1, 0, 0, 0);
        ac2 = __builtin_amdgcn_mfma_f32_16x16x32_bf16(af[5].v, ef[5].v, ac2, 0, 0, 0);
        ac3 = __builtin_amdgcn_mfma_f32_16x16x32_bf16(af[7].v, ef[7].v, ac3, 0, 0, 0);

        if (wr) {
            float y  = (ac0[0] + ac1[0]) + (ac2[0] + ac3[0]);
            float xa = (u_cur - hval) - y;      // u - (h + E h)
            // tanh(x) = 1 - 2/(e^{2x}+1); graceful at +/-inf, no clamp needed
            float E2 = __expf(2.0f * xa);
            float th = fmaf(-2.0f, __builtin_amdgcn_rcpf(E2 + 1.0f), 1.0f);
            hval = fmaf(DT_STEP, th, hval);
            hp[(size_t)t * BH] = hval;
            // pack (col, col+1) -> u32, store into next A-buffer
            int nb = __builtin_amdgcn_mov_dpp(__float_as_int(hval), 0xB1, 0xF, 0xF, true);
            if ((l & 1) == 0) {
                unsigned int pk;
                asm volatile("v_cvt_pk_bf16_f32 %0, %1, %2"
                             : "=v"(pk) : "v"(hval), "v"(__int_as_float(nb)));
                *(unsigned int*)(lds + (roff ^ 9216) + wby) = pk;
            }
        }
        u_cur = u_nxt;
        u_nxt = u_n2;
        roff ^= 9216;
        LBAR();
    }
    if (wr) hfin[(size_t)b * NH + col] = hval;
}

extern "C" void kernel_launch(void* const* d_in, const int* in_sizes, int n_in,
                              void* d_out, int out_size, void* d_ws, size_t ws_size,
                              hipStream_t stream) {
    const float* x     = (const float*)d_in[0];  // [T,B,D]
    const float* U_w   = (const float*)d_in[1];  // [H,D]
    const float* U_b   = (const float*)d_in[2];  // [H]
    const float* W_log = (const float*)d_in[3];  // [H,H]
    const float* c_w   = (const float*)d_in[4];  // [O,H]
    const float* c_b   = (const float*)d_in[5];  // [O]

    float* out    = (float*)d_out;
    float* hidden = out;                          // stage hidden in d_out, then in-place GEMM
    float* hfin   = out + (long)T_STEPS * BH;     // second output chunk

    float* ws = (float*)d_ws;
    float* S  = ws;                // 65536 floats: Wexp accumulator
    float* Pa = ws + 65536;
    float* Pb = ws + 2 * 65536;
    float* u  = ws + 3 * 65536;    // 16,777,216 floats

    // Wexp = expm(W_log), Taylor K=9 (||W_log||_2 ~ 0.32 -> remainder ~1e-9)
    k_init_S<<<64, 1024, 0, stream>>>(W_log, S);
    const float* prev = W_log;
    float* cur = Pa;
    for (int k = 2; k <= 9; ++k) {
        k_expm_term<<<256, 256, 0, stream>>>(prev, W_log, cur, S, 1.0f / (float)k);
        prev = cur;
        cur = (cur == Pa) ? Pb : Pa;
    }

    // u = x @ U_w^T + U_b
    k_gemm_rows<<<4096, 256, 0, stream>>>(x, U_w, U_b, u);

    // sequential recurrence (MFMA), hidden -> d_out
    k_scan_mfma<<<NB, 1024, 0, stream>>>(u, S, hidden, hfin);

    // out = hidden @ c_w^T + c_b, in place
    k_gemm_rows<<<4096, 256, 0, stream>>>(hidden, c_w, c_b, hidden);
}

// Round 9
// 2491.271 us; speedup vs baseline: 1.0168x; 1.0168x over previous
//
#include <hip/hip_runtime.h>
#include <math.h>

#define T_STEPS 4096
#define NB 16          // batch
#define NH 256         // hidden
#define BH (NB * NH)   // 4096 floats per time step
#define DT_STEP 0.1f

typedef __attribute__((ext_vector_type(8))) short short8;
typedef __attribute__((ext_vector_type(4))) float f32x4;

// ---------------- expm via Taylor series ----------------
__global__ __launch_bounds__(1024) void k_init_S(const float* __restrict__ A,
                                                 float* __restrict__ S) {
    int idx = blockIdx.x * 1024 + threadIdx.x;
    int i = idx >> 8, j = idx & 255;
    S[idx] = A[idx] + (i == j ? 1.0f : 0.0f);
}

__global__ __launch_bounds__(256) void k_expm_term(const float* __restrict__ Pprev,
                                                   const float* __restrict__ A,
                                                   float* __restrict__ Pnew,
                                                   float* __restrict__ S,
                                                   float invk) {
    __shared__ float prow[256];
    int i = blockIdx.x, j = threadIdx.x;
    prow[j] = Pprev[i * 256 + j];
    __syncthreads();
    float acc = 0.f;
#pragma unroll 8
    for (int m = 0; m < 256; ++m) acc = fmaf(prow[m], A[m * 256 + j], acc);
    float v = acc * invk;
    Pnew[i * 256 + j] = v;
    S[i * 256 + j] += v;
}

// ---------------- row-blocked GEMM (unchanged, works) ----------------
__global__ __launch_bounds__(256) void k_gemm_rows(const float* __restrict__ X,
                                                   const float* __restrict__ Wm,
                                                   const float* __restrict__ bias,
                                                   float* __restrict__ Out) {
    __shared__ float4 xs4[16][64];
    const int tid = threadIdx.x;
    const long r0 = (long)blockIdx.x * 16;
    float* xs = (float*)xs4;
#pragma unroll
    for (int rr = 0; rr < 16; ++rr) xs[rr * 256 + tid] = X[(r0 + rr) * 256 + tid];
    __syncthreads();

    float acc[16];
#pragma unroll
    for (int rr = 0; rr < 16; ++rr) acc[rr] = 0.f;

    const float4* wrow = (const float4*)(Wm + tid * 256);
    for (int d4 = 0; d4 < 64; ++d4) {
        float4 w = wrow[d4];
#pragma unroll
        for (int rr = 0; rr < 16; ++rr) {
            float4 xv = xs4[rr][d4];
            acc[rr] = fmaf(w.x, xv.x, acc[rr]);
            acc[rr] = fmaf(w.y, xv.y, acc[rr]);
            acc[rr] = fmaf(w.z, xv.z, acc[rr]);
            acc[rr] = fmaf(w.w, xv.w, acc[rr]);
        }
    }
    float b = bias[tid];
#pragma unroll
    for (int rr = 0; rr < 16; ++rr) Out[(r0 + rr) * 256 + tid] = acc[rr] + b;
}

// ---------------- MFMA scan, operand-swapped: one block (CU) per batch ----------------
// y = E@h (E = Wexp - I as bf16 A-operand, rows = n); h replicated across the
// 16 B-columns (broadcast LDS reads). 4 waves x 4 n-tile chains x 8 kt = 128
// MFMA/step, no zero padding. C[row=n-local][col=replica] -> every lane owns
// exactly one h-update: n = 64w | ((l>>2)&3)<<4 | (l>>4)<<2 | (l&3).
// h lives in LDS as 512B linear bf16, double-buffered; DS ops per step:
// 8 broadcast ds_read_b128 + 1 ds_write_b32 per wave (vs 128 reads before).
__global__ __launch_bounds__(256)
__attribute__((amdgpu_waves_per_eu(1, 1)))
void k_scan_bc(const float* __restrict__ u,
               const float* S,        // Wexp (f32); no restrict: discourage remat
               float* hidden,
               float* __restrict__ hfin) {
    const int b   = blockIdx.x;
    const int tid = threadIdx.x;
    const int w   = tid >> 6;           // wave 0..3, owns n-tiles 4w..4w+3
    const int l   = tid & 63;
    const int lg  = l >> 4;             // k-group 0..3
    const int lr  = l & 15;             // row within n-tile

    __shared__ unsigned int hlds[256];  // 2 x 512B: h as bf16, linear, dbuf
    char* lds = (char*)hlds;

    union Frag { unsigned int u[4]; short8 v; };

    // ---- A-fragments: E rows for 4 chains x 8 kt (128 VGPRs if resident) ----
    Frag ef[4][8];
#pragma unroll
    for (int j = 0; j < 4; ++j) {
        const int n = ((4 * w + j) << 4) | lr;
#pragma unroll
        for (int kt = 0; kt < 8; ++kt) {
            const int k0 = kt * 32 + lg * 8;
            const float* sp = S + (size_t)n * 256 + k0;
            float e[8];
#pragma unroll
            for (int q = 0; q < 8; ++q)
                e[q] = sp[q] - ((n == k0 + q) ? 1.0f : 0.0f);
#pragma unroll
            for (int r2 = 0; r2 < 4; ++r2) {
                unsigned int pk;
                asm volatile("v_cvt_pk_bf16_f32 %0, %1, %2"
                             : "=v"(pk) : "v"(e[2 * r2]), "v"(e[2 * r2 + 1]));
                ef[j][kt].u[r2] = pk;
            }
        }
    }

    // ---- per-lane owned h element ----
    const int j_own = (l >> 2) & 3;
    const int n_own = (w << 6) | (j_own << 4) | (lg << 2) | (l & 3);

    if (tid < 256) hlds[tid] = 0u;      // zero both h buffers

    const float* up = u + (size_t)b * NH + n_own;
    float* hp = hidden + (size_t)b * NH + n_own;

    float hval = 0.f;
    float u_cur = up[0];
    float u_nxt = up[BH];
    __syncthreads();

    int roff = 0;                        // byte offset of read buffer (0/512)
    for (int t = 0; t < T_STEPS; ++t) {
        const int tpre = (t + 2 < T_STEPS) ? (t + 2) : (T_STEPS - 1);
        float u_n2 = up[(size_t)tpre * BH];

        // B-fragments: h broadcast (same 16B per 16-lane group)
        Frag hb[8];
#pragma unroll
        for (int kt = 0; kt < 8; ++kt)
            hb[kt].v = *(const short8*)(lds + roff + kt * 64 + lg * 16);

        // 4 independent chains (one per n-tile)
        f32x4 ac0 = {0.f, 0.f, 0.f, 0.f};
        f32x4 ac1 = {0.f, 0.f, 0.f, 0.f};
        f32x4 ac2 = {0.f, 0.f, 0.f, 0.f};
        f32x4 ac3 = {0.f, 0.f, 0.f, 0.f};
#pragma unroll
        for (int kt = 0; kt < 8; ++kt) {
            ac0 = __builtin_amdgcn_mfma_f32_16x16x32_bf16(ef[0][kt].v, hb[kt].v, ac0, 0, 0, 0);
            ac1 = __builtin_amdgcn_mfma_f32_16x16x32_bf16(ef[1][kt].v, hb[kt].v, ac1, 0, 0, 0);
            ac2 = __builtin_amdgcn_mfma_f32_16x16x32_bf16(ef[2][kt].v, hb[kt].v, ac2, 0, 0, 0);
            ac3 = __builtin_amdgcn_mfma_f32_16x16x32_bf16(ef[3][kt].v, hb[kt].v, ac3, 0, 0, 0);
        }

        // select this lane's y: chain j_own, reg l&3 (all compile-time indices)
        f32x4 ca = (j_own & 1) ? ac1 : ac0;
        f32x4 cb = (j_own & 1) ? ac3 : ac2;
        f32x4 cc = (j_own & 2) ? cb : ca;
        float y01 = (l & 1) ? cc[1] : cc[0];
        float y23 = (l & 1) ? cc[3] : cc[2];
        float y   = (l & 2) ? y23 : y01;

        // h += dt * tanh(u - (h + E h));  tanh(x) = 1 - 2/(e^{2x}+1)
        float xa = (u_cur - hval) - y;
        float E2 = __expf(2.0f * xa);
        float th = fmaf(-2.0f, __builtin_amdgcn_rcpf(E2 + 1.0f), 1.0f);
        hval = fmaf(DT_STEP, th, hval);
        hp[(size_t)t * BH] = hval;

        // pack (n_own even, n_own+1) -> dword into next buffer
        int nb = __builtin_amdgcn_mov_dpp(__float_as_int(hval), 0xB1, 0xF, 0xF, true);
        if ((l & 1) == 0) {
            unsigned int pk;
            asm volatile("v_cvt_pk_bf16_f32 %0, %1, %2"
                         : "=v"(pk) : "v"(hval), "v"(__int_as_float(nb)));
            *(unsigned int*)(lds + (roff ^ 512) + ((n_own >> 1) << 2)) = pk;
        }
        u_cur = u_nxt;
        u_nxt = u_n2;
        roff ^= 512;
        __syncthreads();
    }
    hfin[(size_t)b * NH + n_own] = hval;
}

extern "C" void kernel_launch(void* const* d_in, const int* in_sizes, int n_in,
                              void* d_out, int out_size, void* d_ws, size_t ws_size,
                              hipStream_t stream) {
    const float* x     = (const float*)d_in[0];  // [T,B,D]
    const float* U_w   = (const float*)d_in[1];  // [H,D]
    const float* U_b   = (const float*)d_in[2];  // [H]
    const float* W_log = (const float*)d_in[3];  // [H,H]
    const float* c_w   = (const float*)d_in[4];  // [O,H]
    const float* c_b   = (const float*)d_in[5];  // [O]

    float* out    = (float*)d_out;
    float* hidden = out;                          // stage hidden in d_out, then in-place GEMM
    float* hfin   = out + (long)T_STEPS * BH;     // second output chunk

    float* ws = (float*)d_ws;
    float* S  = ws;                // 65536 floats: Wexp accumulator
    float* Pa = ws + 65536;
    float* Pb = ws + 2 * 65536;
    float* u  = ws + 3 * 65536;    // 16,777,216 floats

    // Wexp = expm(W_log), Taylor K=9 (||W_log||_2 ~ 0.32 -> remainder ~1e-9)
    k_init_S<<<64, 1024, 0, stream>>>(W_log, S);
    const float* prev = W_log;
    float* cur = Pa;
    for (int k = 2; k <= 9; ++k) {
        k_expm_term<<<256, 256, 0, stream>>>(prev, W_log, cur, S, 1.0f / (float)k);
        prev = cur;
        cur = (cur == Pa) ? Pb : Pa;
    }

    // u = x @ U_w^T + U_b
    k_gemm_rows<<<4096, 256, 0, stream>>>(x, U_w, U_b, u);

    // sequential recurrence (operand-swapped MFMA), hidden -> d_out
    k_scan_bc<<<NB, 256, 0, stream>>>(u, S, hidden, hfin);

    // out = hidden @ c_w^T + c_b, in place
    k_gemm_rows<<<4096, 256, 0, stream>>>(hidden, c_w, c_b, hidden);
}

// Round 10
// 2328.935 us; speedup vs baseline: 1.0877x; 1.0697x over previous
//
#include <hip/hip_runtime.h>
#include <math.h>

#define T_STEPS 4096
#define NB 16          // batch
#define NH 256         // hidden
#define BH (NB * NH)   // 4096 floats per time step
#define DT_STEP 0.1f

typedef __attribute__((ext_vector_type(8))) short short8;
typedef __attribute__((ext_vector_type(4))) float f32x4;

// ---------------- expm via Taylor series ----------------
__global__ __launch_bounds__(1024) void k_init_S(const float* __restrict__ A,
                                                 float* __restrict__ S) {
    int idx = blockIdx.x * 1024 + threadIdx.x;
    int i = idx >> 8, j = idx & 255;
    S[idx] = A[idx] + (i == j ? 1.0f : 0.0f);
}

__global__ __launch_bounds__(256) void k_expm_term(const float* __restrict__ Pprev,
                                                   const float* __restrict__ A,
                                                   float* __restrict__ Pnew,
                                                   float* __restrict__ S,
                                                   float invk) {
    __shared__ float prow[256];
    int i = blockIdx.x, j = threadIdx.x;
    prow[j] = Pprev[i * 256 + j];
    __syncthreads();
    float acc = 0.f;
#pragma unroll 8
    for (int m = 0; m < 256; ++m) acc = fmaf(prow[m], A[m * 256 + j], acc);
    float v = acc * invk;
    Pnew[i * 256 + j] = v;
    S[i * 256 + j] += v;
}

// ---------------- row-blocked GEMM (unchanged, works) ----------------
__global__ __launch_bounds__(256) void k_gemm_rows(const float* __restrict__ X,
                                                   const float* __restrict__ Wm,
                                                   const float* __restrict__ bias,
                                                   float* __restrict__ Out) {
    __shared__ float4 xs4[16][64];
    const int tid = threadIdx.x;
    const long r0 = (long)blockIdx.x * 16;
    float* xs = (float*)xs4;
#pragma unroll
    for (int rr = 0; rr < 16; ++rr) xs[rr * 256 + tid] = X[(r0 + rr) * 256 + tid];
    __syncthreads();

    float acc[16];
#pragma unroll
    for (int rr = 0; rr < 16; ++rr) acc[rr] = 0.f;

    const float4* wrow = (const float4*)(Wm + tid * 256);
    for (int d4 = 0; d4 < 64; ++d4) {
        float4 w = wrow[d4];
#pragma unroll
        for (int rr = 0; rr < 16; ++rr) {
            float4 xv = xs4[rr][d4];
            acc[rr] = fmaf(w.x, xv.x, acc[rr]);
            acc[rr] = fmaf(w.y, xv.y, acc[rr]);
            acc[rr] = fmaf(w.z, xv.z, acc[rr]);
            acc[rr] = fmaf(w.w, xv.w, acc[rr]);
        }
    }
    float b = bias[tid];
#pragma unroll
    for (int rr = 0; rr < 16; ++rr) Out[(r0 + rr) * 256 + tid] = acc[rr] + b;
}

// ---------------- MFMA scan v3: 8 waves, depth-2 chains ----------------
// y = E@h (E = Wexp - I bf16 A-operand; h broadcast as B across 16 cols).
// 8 waves (2/SIMD): wave w owns n-tiles 2w, 2w+1. Per n-tile 4 accumulators
// (kt pairs g/g+4, chain depth 2) -> 16 indep chains/SIMD: MFMA issue-bound,
// not latency-bound. 2 waves/SIMD overlap VALU tail with MFMA. h in LDS as
// 512B linear bf16, double-buffered; broadcast ds_reads; one barrier/step.
// Lane ownership: j = (l>>2)&1, n_own = (2w+j)<<4 | (l>>4)<<2 | (l&3)
// (bit 3 of lane unused -> lanes l and l|8 duplicate; only l&8==0 store).
__global__ __launch_bounds__(512)
__attribute__((amdgpu_waves_per_eu(2, 2)))
void k_scan_bc2(const float* __restrict__ u,
                const float* S,        // Wexp (f32); no restrict
                float* hidden,
                float* __restrict__ hfin) {
    const int b   = blockIdx.x;
    const int tid = threadIdx.x;
    const int w   = tid >> 6;           // wave 0..7: n-tiles 2w, 2w+1
    const int l   = tid & 63;
    const int lg  = l >> 4;             // k-group 0..3
    const int lr  = l & 15;             // row within n-tile

    __shared__ unsigned int hlds[256];  // 2 x 512B: h as bf16, linear, dbuf
    char* lds = (char*)hlds;

    union Frag { unsigned int u[4]; short8 v; };

    // ---- A-fragments: E rows for 2 n-tiles x 8 kt = 64 VGPRs ----
    Frag ef[2][8];
#pragma unroll
    for (int j = 0; j < 2; ++j) {
        const int n = ((2 * w + j) << 4) | lr;
#pragma unroll
        for (int kt = 0; kt < 8; ++kt) {
            const int k0 = kt * 32 + lg * 8;
            const float* sp = S + (size_t)n * 256 + k0;
            float e[8];
#pragma unroll
            for (int q = 0; q < 8; ++q)
                e[q] = sp[q] - ((n == k0 + q) ? 1.0f : 0.0f);
#pragma unroll
            for (int r2 = 0; r2 < 4; ++r2) {
                unsigned int pk;
                asm volatile("v_cvt_pk_bf16_f32 %0, %1, %2"
                             : "=v"(pk) : "v"(e[2 * r2]), "v"(e[2 * r2 + 1]));
                ef[j][kt].u[r2] = pk;
            }
        }
    }

    // ---- per-lane owned h element (lanes l and l|8 duplicate) ----
    const int j_own = (l >> 2) & 1;
    const int n_own = ((2 * w + j_own) << 4) | ((l >> 4) << 2) | (l & 3);
    const bool st = ((l & 8) == 0);       // storer lanes
    const bool wrt = ((l & 9) == 0);      // LDS writer lanes (even pair leader)

    if (tid < 256) hlds[tid] = 0u;        // zero both h buffers

    const float* up = u + (size_t)b * NH + n_own;
    float* hp = hidden + (size_t)b * NH + n_own;
    const float* upn = up + 2 * BH;       // walking prefetch pointer

    float hval = 0.f;
    float u_cur = up[0];
    float u_nxt = up[BH];
    __syncthreads();

    int roff = 0;                         // byte offset of read buffer (0/512)
    for (int t = 0; t < T_STEPS; ++t) {
        float u_n2 = *upn;
        upn += (t + 3 < T_STEPS) ? BH : 0;

        // B-fragments: h broadcast (same 16B per 16-lane group)
        Frag hb[8];
#pragma unroll
        for (int kt = 0; kt < 8; ++kt)
            hb[kt].v = *(const short8*)(lds + roff + kt * 64 + lg * 16);

        // 16 independent depth-2 chains per SIMD (2 waves x 2 tiles x 4 accs)
        f32x4 a00 = {0,0,0,0}, a01 = {0,0,0,0}, a02 = {0,0,0,0}, a03 = {0,0,0,0};
        f32x4 a10 = {0,0,0,0}, a11 = {0,0,0,0}, a12 = {0,0,0,0}, a13 = {0,0,0,0};
        a00 = __builtin_amdgcn_mfma_f32_16x16x32_bf16(ef[0][0].v, hb[0].v, a00, 0, 0, 0);
        a01 = __builtin_amdgcn_mfma_f32_16x16x32_bf16(ef[0][1].v, hb[1].v, a01, 0, 0, 0);
        a02 = __builtin_amdgcn_mfma_f32_16x16x32_bf16(ef[0][2].v, hb[2].v, a02, 0, 0, 0);
        a03 = __builtin_amdgcn_mfma_f32_16x16x32_bf16(ef[0][3].v, hb[3].v, a03, 0, 0, 0);
        a10 = __builtin_amdgcn_mfma_f32_16x16x32_bf16(ef[1][0].v, hb[0].v, a10, 0, 0, 0);
        a11 = __builtin_amdgcn_mfma_f32_16x16x32_bf16(ef[1][1].v, hb[1].v, a11, 0, 0, 0);
        a12 = __builtin_amdgcn_mfma_f32_16x16x32_bf16(ef[1][2].v, hb[2].v, a12, 0, 0, 0);
        a13 = __builtin_amdgcn_mfma_f32_16x16x32_bf16(ef[1][3].v, hb[3].v, a13, 0, 0, 0);
        a00 = __builtin_amdgcn_mfma_f32_16x16x32_bf16(ef[0][4].v, hb[4].v, a00, 0, 0, 0);
        a01 = __builtin_amdgcn_mfma_f32_16x16x32_bf16(ef[0][5].v, hb[5].v, a01, 0, 0, 0);
        a02 = __builtin_amdgcn_mfma_f32_16x16x32_bf16(ef[0][6].v, hb[6].v, a02, 0, 0, 0);
        a03 = __builtin_amdgcn_mfma_f32_16x16x32_bf16(ef[0][7].v, hb[7].v, a03, 0, 0, 0);
        a10 = __builtin_amdgcn_mfma_f32_16x16x32_bf16(ef[1][4].v, hb[4].v, a10, 0, 0, 0);
        a11 = __builtin_amdgcn_mfma_f32_16x16x32_bf16(ef[1][5].v, hb[5].v, a11, 0, 0, 0);
        a12 = __builtin_amdgcn_mfma_f32_16x16x32_bf16(ef[1][6].v, hb[6].v, a12, 0, 0, 0);
        a13 = __builtin_amdgcn_mfma_f32_16x16x32_bf16(ef[1][7].v, hb[7].v, a13, 0, 0, 0);

        // select j_own per accumulator group, tree-add, component select
        f32x4 c0 = j_own ? a10 : a00;
        f32x4 c1 = j_own ? a11 : a01;
        f32x4 c2 = j_own ? a12 : a02;
        f32x4 c3 = j_own ? a13 : a03;
        f32x4 s = (c0 + c1) + (c2 + c3);
        float y01 = (l & 1) ? s[1] : s[0];
        float y23 = (l & 1) ? s[3] : s[2];
        float y   = (l & 2) ? y23 : y01;

        // h += dt * tanh(u - (h + E h));  tanh(x) = 1 - 2/(e^{2x}+1)
        float xa = (u_cur - hval) - y;
        float E2 = __expf(2.0f * xa);
        float th = fmaf(-2.0f, __builtin_amdgcn_rcpf(E2 + 1.0f), 1.0f);
        hval = fmaf(DT_STEP, th, hval);
        if (st) hp[0] = hval;
        hp += BH;

        // pack (n_own even, n_own+1) -> dword into next buffer
        int nb = __builtin_amdgcn_mov_dpp(__float_as_int(hval), 0xB1, 0xF, 0xF, true);
        if (wrt) {
            unsigned int pk;
            asm volatile("v_cvt_pk_bf16_f32 %0, %1, %2"
                         : "=v"(pk) : "v"(hval), "v"(__int_as_float(nb)));
            *(unsigned int*)(lds + (roff ^ 512) + ((n_own >> 1) << 2)) = pk;
        }
        u_cur = u_nxt;
        u_nxt = u_n2;
        roff ^= 512;
        __syncthreads();
    }
    if (st) hfin[(size_t)b * NH + n_own] = hval;
}

extern "C" void kernel_launch(void* const* d_in, const int* in_sizes, int n_in,
                              void* d_out, int out_size, void* d_ws, size_t ws_size,
                              hipStream_t stream) {
    const float* x     = (const float*)d_in[0];  // [T,B,D]
    const float* U_w   = (const float*)d_in[1];  // [H,D]
    const float* U_b   = (const float*)d_in[2];  // [H]
    const float* W_log = (const float*)d_in[3];  // [H,H]
    const float* c_w   = (const float*)d_in[4];  // [O,H]
    const float* c_b   = (const float*)d_in[5];  // [O]

    float* out    = (float*)d_out;
    float* hidden = out;                          // stage hidden in d_out, then in-place GEMM
    float* hfin   = out + (long)T_STEPS * BH;     // second output chunk

    float* ws = (float*)d_ws;
    float* S  = ws;                // 65536 floats: Wexp accumulator
    float* Pa = ws + 65536;
    float* Pb = ws + 2 * 65536;
    float* u  = ws + 3 * 65536;    // 16,777,216 floats

    // Wexp = expm(W_log), Taylor K=9 (||W_log||_2 ~ 0.32 -> remainder ~1e-9)
    k_init_S<<<64, 1024, 0, stream>>>(W_log, S);
    const float* prev = W_log;
    float* cur = Pa;
    for (int k = 2; k <= 9; ++k) {
        k_expm_term<<<256, 256, 0, stream>>>(prev, W_log, cur, S, 1.0f / (float)k);
        prev = cur;
        cur = (cur == Pa) ? Pb : Pa;
    }

    // u = x @ U_w^T + U_b
    k_gemm_rows<<<4096, 256, 0, stream>>>(x, U_w, U_b, u);

    // sequential recurrence (8-wave MFMA, depth-2 chains), hidden -> d_out
    k_scan_bc2<<<NB, 512, 0, stream>>>(u, S, hidden, hfin);

    // out = hidden @ c_w^T + c_b, in place
    k_gemm_rows<<<4096, 256, 0, stream>>>(hidden, c_w, c_b, hidden);
}